// Round 1
// baseline (181.260 us; speedup 1.0000x reference)
//
#include <hip/hip_runtime.h>

// Site-id domain: x*NUM_SITES_Y + y with 2048*4096 = 8,388,608 ids -> 1 MiB bitmap.
static constexpr int NUM_SITES_TOTAL = 2048 * 4096;          // 8,388,608
static constexpr int BITMAP_WORDS    = NUM_SITES_TOTAL / 32; // 262,144 (1 MiB)

// ---------------------------------------------------------------------------
// Kernel 1: zero the bitmap (d_ws is poisoned to 0xAA before every launch).
// 262,144 words / 4 per uint4 = 65,536 threads.
__global__ __launch_bounds__(256) void zero_bitmap_kernel(uint4* __restrict__ bm) {
    int i = blockIdx.x * blockDim.x + threadIdx.x;
    bm[i] = make_uint4(0u, 0u, 0u, 0u);
}

// ---------------------------------------------------------------------------
// Kernel 2: mark assigned sites. addr2site_map is sorted, so consecutive
// entries often land in the same bitmap word -> merge bits per-thread before
// the atomicOr to cut atomic traffic.
__global__ __launch_bounds__(256) void mark_assigned_kernel(
    const int4* __restrict__ sig, const int4* __restrict__ a2s,
    unsigned int* __restrict__ bm, int n4) {
    int i = blockIdx.x * blockDim.x + threadIdx.x;
    if (i >= n4) return;
    int4 sg = sig[i];
    int4 am = a2s[i];
    int sgv[4] = {sg.x, sg.y, sg.z, sg.w};
    int amv[4] = {am.x, am.y, am.z, am.w};
    unsigned int curw = 0xFFFFFFFFu, curm = 0u;
#pragma unroll
    for (int j = 0; j < 4; ++j) {
        if (sgv[j] > 0) {
            unsigned int s = (unsigned int)amv[j];
            unsigned int w = s >> 5;
            unsigned int m = 1u << (s & 31u);
            if (w == curw) {
                curm |= m;
            } else {
                if (curm) atomicOr(bm + curw, curm);
                curw = w;
                curm = m;
            }
        }
    }
    if (curm) atomicOr(bm + curw, curm);
}

// Scalar tail (not used at n=6M, kept for robustness).
__global__ void mark_assigned_tail_kernel(
    const int* __restrict__ sig, const int* __restrict__ a2s,
    unsigned int* __restrict__ bm, int start, int n) {
    int i = start + blockIdx.x * blockDim.x + threadIdx.x;
    if (i >= n) return;
    if (sig[i] > 0) {
        unsigned int s = (unsigned int)a2s[i];
        atomicOr(bm + (s >> 5), 1u << (s & 31u));
    }
}

// ---------------------------------------------------------------------------
// Kernel 3: probe bitmap, emit remaining (0/1 as float) and masked scores.
__global__ __launch_bounds__(256) void output_kernel(
    const int4* __restrict__ ss, const float4* __restrict__ sc,
    const unsigned int* __restrict__ bm,
    float4* __restrict__ rem, float4* __restrict__ avail, int n4) {
    int i = blockIdx.x * blockDim.x + threadIdx.x;
    if (i >= n4) return;
    int4 s = ss[i];
    float4 f = sc[i];
    int sv[4] = {s.x, s.y, s.z, s.w};
    float fv[4] = {f.x, f.y, f.z, f.w};
    float rv[4], av[4];
#pragma unroll
    for (int j = 0; j < 4; ++j) {
        unsigned int u = (unsigned int)sv[j];
        unsigned int bit = (bm[u >> 5] >> (u & 31u)) & 1u;
        rv[j] = bit ? 0.0f : 1.0f;
        av[j] = bit ? 0.0f : fv[j];
    }
    rem[i]   = make_float4(rv[0], rv[1], rv[2], rv[3]);
    avail[i] = make_float4(av[0], av[1], av[2], av[3]);
}

__global__ void output_tail_kernel(
    const int* __restrict__ ss, const float* __restrict__ sc,
    const unsigned int* __restrict__ bm,
    float* __restrict__ rem, float* __restrict__ avail, int start, int n) {
    int i = start + blockIdx.x * blockDim.x + threadIdx.x;
    if (i >= n) return;
    unsigned int u = (unsigned int)ss[i];
    unsigned int bit = (bm[u >> 5] >> (u & 31u)) & 1u;
    rem[i]   = bit ? 0.0f : 1.0f;
    avail[i] = bit ? 0.0f : sc[i];
}

extern "C" void kernel_launch(void* const* d_in, const int* in_sizes, int n_in,
                              void* d_out, int out_size, void* d_ws, size_t ws_size,
                              hipStream_t stream) {
    const int*   slice_sites = (const int*)d_in[0];
    const int*   sig         = (const int*)d_in[1];
    const int*   a2s         = (const int*)d_in[2];
    const float* scores      = (const float*)d_in[3];
    const int n_slice = in_sizes[0];
    const int n_clb   = in_sizes[1];

    unsigned int* bm = (unsigned int*)d_ws;  // 1 MiB bitmap

    // 1) zero bitmap
    {
        int threads = BITMAP_WORDS / 4;  // uint4 stores
        zero_bitmap_kernel<<<threads / 256, 256, 0, stream>>>((uint4*)bm);
    }

    // 2) mark assigned sites
    {
        int n4 = n_clb / 4;
        if (n4 > 0)
            mark_assigned_kernel<<<(n4 + 255) / 256, 256, 0, stream>>>(
                (const int4*)sig, (const int4*)a2s, bm, n4);
        int tail = n_clb - n4 * 4;
        if (tail > 0)
            mark_assigned_tail_kernel<<<1, 64, 0, stream>>>(sig, a2s, bm, n4 * 4, n_clb);
    }

    // 3) probe + write outputs: d_out = [remaining(float 0/1) | avail_scores]
    {
        float* rem   = (float*)d_out;
        float* avail = rem + n_slice;
        int n4 = n_slice / 4;
        if (n4 > 0)
            output_kernel<<<(n4 + 255) / 256, 256, 0, stream>>>(
                (const int4*)slice_sites, (const float4*)scores, bm,
                (float4*)rem, (float4*)avail, n4);
        int tail = n_slice - n4 * 4;
        if (tail > 0)
            output_tail_kernel<<<1, 64, 0, stream>>>(slice_sites, scores, bm,
                                                     rem, avail, n4 * 4, n_slice);
    }
}